// Round 3
// baseline (76.849 us; speedup 1.0000x reference)
//
#include <hip/hip_runtime.h>
#include <limits.h>

#define HB 16
#define HH 96
#define HW 96
#define HN (HH*HW)
#define WPR 3              // u32 words per mask row
#define WPI (HH*WPR)       // 288 words per image mask
#define TPB 1024
#define PXT (HN/TPB)       // 9 pixels per thread

// nearest |x - x'| over set bits of a 96-bit row (lo = bits 0..63, hi = 64..95).
// Row must be non-empty; result <= 95.
__device__ __forceinline__ int nearest_dx(unsigned long long lo, unsigned int hi, int x) {
    int dr = 1 << 20, dl = 1 << 20;
    if (x < 64) {
        unsigned long long r = lo >> x;
        if (r) dr = __builtin_ctzll(r);
        else if (hi) dr = (64 - x) + __builtin_ctz(hi);
        unsigned long long lm = lo << (63 - x);      // bit x -> bit 63
        if (lm) dl = __builtin_clzll(lm);
    } else {
        int xh = x - 64;                             // 0..31
        unsigned int r = hi >> xh;
        if (r) dr = __builtin_ctz(r);
        unsigned int lmh = hi << (31 - xh);          // bit xh -> bit 31
        if (lmh) dl = __builtin_clz(lmh);
        else if (lo) dl = (xh + 1) + __builtin_clzll(lo);
    }
    return min(dl, dr);
}

// farthest |x - x'| over set bits of a non-empty 96-bit row.
__device__ __forceinline__ int farthest_dx(unsigned long long lo, unsigned int hi, int x) {
    int first = lo ? __builtin_ctzll(lo) : 64 + __builtin_ctz(hi);
    int last  = hi ? 95 - __builtin_clz(hi) : 63 - __builtin_clzll(lo);
    return max(x - first, last - x);
}

// squared distance from (y,x) to nearest set pixel in mask m (96 rows x 3 words).
// Expanding-ring search: break when dy^2 >= best. Mask must be non-empty.
__device__ __forceinline__ int search2d(const unsigned int* m, int y, int x) {
    int best = INT_MAX;
    for (int dy = 0; dy < HH; ++dy) {
        if (dy * dy >= best) break;
        int yl = y - dy;
        if (yl >= 0) {
            unsigned long long lo = (unsigned long long)m[yl*WPR] |
                                    ((unsigned long long)m[yl*WPR+1] << 32);
            unsigned int hi = m[yl*WPR+2];
            if (lo | hi) {
                int dx = nearest_dx(lo, hi, x);
                best = min(best, dy*dy + dx*dx);
            }
        }
        int yh = y + dy;
        if (dy > 0 && yh < HH) {
            unsigned long long lo = (unsigned long long)m[yh*WPR] |
                                    ((unsigned long long)m[yh*WPR+1] << 32);
            unsigned int hi = m[yh*WPR+2];
            if (lo | hi) {
                int dx = nearest_dx(lo, hi, x);
                best = min(best, dy*dy + dx*dx);
            }
        }
    }
    return best;
}

// squared distance from (y,x) to FARTHEST set pixel in mask m. For the
// empty-set diameter fallback only (dead for these inputs).
__device__ __forceinline__ int farthest2d(const unsigned int* m, int y, int x) {
    int best = 0;
    for (int yy = 0; yy < HH; ++yy) {
        unsigned long long lo = (unsigned long long)m[yy*WPR] |
                                ((unsigned long long)m[yy*WPR+1] << 32);
        unsigned int hi = m[yy*WPR+2];
        if (lo | hi) {
            int fd = farthest_dx(lo, hi, x);
            int dy = yy - y;
            best = max(best, dy*dy + fd*fd);
        }
    }
    return best;
}

// One block per image. Build LDS bitmasks -> per-pixel ring search -> reduce
// -> empty-set rules -> atomicAdd of hd/B into out.
__global__ __launch_bounds__(TPB) void hausdorff_fused(const float* __restrict__ pred,
                                                       const float* __restrict__ targ,
                                                       float* __restrict__ out) {
    int img = blockIdx.x;
    int tid = threadIdx.x;
    __shared__ unsigned int sA[WPI], sB[WPI];
    __shared__ int redAB, redBA;
    __shared__ int fA, fB;

    if (tid == 0) { redAB = -1; redBA = -1; fA = 0; fB = 0; }

    // ---- build masks: thread t < 2*WPI packs one 32-bit word (32 consecutive px)
    if (tid < 2 * WPI) {
        int set = tid >= WPI;
        int w   = set ? tid - WPI : tid;
        const float* src = (set ? targ : pred) + img * HN + 32 * w;
        const float4* v4 = reinterpret_cast<const float4*>(src);
        unsigned int bits = 0;
        #pragma unroll
        for (int j = 0; j < 8; ++j) {
            float4 v = v4[j];
            if (v.x >= 0.5f) bits |= 1u << (4*j + 0);
            if (v.y >= 0.5f) bits |= 1u << (4*j + 1);
            if (v.z >= 0.5f) bits |= 1u << (4*j + 2);
            if (v.w >= 0.5f) bits |= 1u << (4*j + 3);
        }
        (set ? sB : sA)[w] = bits;
        if (bits) { if (set) fB = 1; else fA = 1; }   // benign race: all write 1
    }
    __syncthreads();

    bool anyA = fA != 0, anyB = fB != 0;   // block-uniform
    int lAB = -1, lBA = -1;

    if (anyA && anyB) {
        #pragma unroll
        for (int k = 0; k < PXT; ++k) {
            int li = k * TPB + tid;
            int y  = li / HW;
            int x  = li - y * HW;
            bool a = (sA[y*WPR + (x>>5)] >> (x & 31)) & 1u;
            bool b = (sB[y*WPR + (x>>5)] >> (x & 31)) & 1u;
            if (a) lAB = max(lAB, search2d(sB, y, x));   // A-point -> set B
            if (b) lBA = max(lBA, search2d(sA, y, x));   // B-point -> set A
        }
    } else if (anyA) {
        // B empty -> diameter of A (dead for these inputs, kept for correctness)
        for (int k = 0; k < PXT; ++k) {
            int li = k * TPB + tid;
            int y  = li / HW;
            int x  = li - y * HW;
            bool a = (sA[y*WPR + (x>>5)] >> (x & 31)) & 1u;
            if (a) lAB = max(lAB, farthest2d(sA, y, x));
        }
    } else if (anyB) {
        for (int k = 0; k < PXT; ++k) {
            int li = k * TPB + tid;
            int y  = li / HW;
            int x  = li - y * HW;
            bool b = (sB[y*WPR + (x>>5)] >> (x & 31)) & 1u;
            if (b) lBA = max(lBA, farthest2d(sB, y, x));
        }
    }

    // ---- reduce: 6-step wave shuffle max, then one LDS atomic per wave
    #pragma unroll
    for (int off = 32; off >= 1; off >>= 1) {
        lAB = max(lAB, __shfl_down(lAB, off, 64));
        lBA = max(lBA, __shfl_down(lBA, off, 64));
    }
    if ((tid & 63) == 0) {
        atomicMax(&redAB, lAB);
        atomicMax(&redBA, lBA);
    }
    __syncthreads();

    if (tid == 0) {
        float hd;
        if (anyA && anyB)      hd = sqrtf((float)max(redAB, redBA));
        else if (anyA)         hd = sqrtf((float)redAB);   // diam(A)^2
        else if (anyB)         hd = sqrtf((float)redBA);   // diam(B)^2
        else                   hd = 0.0f;
        atomicAdd(out, hd * (1.0f / HB));
    }
}

extern "C" void kernel_launch(void* const* d_in, const int* in_sizes, int n_in,
                              void* d_out, int out_size, void* d_ws, size_t ws_size,
                              hipStream_t stream) {
    const float* pred = (const float*)d_in[0];
    const float* targ = (const float*)d_in[1];
    float* out = (float*)d_out;

    hipMemsetAsync(out, 0, sizeof(float), stream);   // accumulator for the mean
    hausdorff_fused<<<HB, TPB, 0, stream>>>(pred, targ, out);
}

// Round 4
// 69.788 us; speedup vs baseline: 1.1012x; 1.1012x over previous
//
#include <hip/hip_runtime.h>
#include <limits.h>

#define HB 16
#define HH 96
#define HW 96
#define HN (HH*HW)
#define WPR 3                   // u32 words per mask row
#define WPI (HH*WPR)            // 288 words per image mask
#define STRIPES 12
#define ROWS_PER (HH/STRIPES)   // 8 rows per stripe
#define PX_PER (ROWS_PER*HW)    // 768 px per stripe
#define TPB 256
#define NBLK (HB*STRIPES)       // 192 blocks

// nearest |x - x'| over set bits of a 96-bit row (lo = bits 0..63, hi = 64..95).
// Row must be non-empty; result <= 95. (Verified absmax=0 in R2/R3.)
__device__ __forceinline__ int nearest_dx(unsigned long long lo, unsigned int hi, int x) {
    int dr = 1 << 20, dl = 1 << 20;
    if (x < 64) {
        unsigned long long r = lo >> x;
        if (r) dr = __builtin_ctzll(r);
        else if (hi) dr = (64 - x) + __builtin_ctz(hi);
        unsigned long long lm = lo << (63 - x);      // bit x -> bit 63
        if (lm) dl = __builtin_clzll(lm);
    } else {
        int xh = x - 64;                             // 0..31
        unsigned int r = hi >> xh;
        if (r) dr = __builtin_ctz(r);
        unsigned int lmh = hi << (31 - xh);          // bit xh -> bit 31
        if (lmh) dl = __builtin_clz(lmh);
        else if (lo) dl = (xh + 1) + __builtin_clzll(lo);
    }
    return min(dl, dr);
}

// farthest |x - x'| over set bits of a non-empty 96-bit row.
__device__ __forceinline__ int farthest_dx(unsigned long long lo, unsigned int hi, int x) {
    int first = lo ? __builtin_ctzll(lo) : 64 + __builtin_ctz(hi);
    int last  = hi ? 95 - __builtin_clz(hi) : 63 - __builtin_clzll(lo);
    return max(x - first, last - x);
}

// squared distance from (y,x) to nearest set pixel in mask m. Expanding-ring
// search, exact: break when dy^2 >= best. Mask must be non-empty.
__device__ __forceinline__ int search2d(const unsigned int* m, int y, int x) {
    int best = INT_MAX;
    for (int dy = 0; dy < HH; ++dy) {
        if (dy * dy >= best) break;
        int yl = y - dy;
        if (yl >= 0) {
            unsigned long long lo = (unsigned long long)m[yl*WPR] |
                                    ((unsigned long long)m[yl*WPR+1] << 32);
            unsigned int hi = m[yl*WPR+2];
            if (lo | hi) best = min(best, dy*dy + [&]{
                int dx = nearest_dx(lo, hi, x); return dx*dx; }());
        }
        int yh = y + dy;
        if (dy > 0 && yh < HH) {
            unsigned long long lo = (unsigned long long)m[yh*WPR] |
                                    ((unsigned long long)m[yh*WPR+1] << 32);
            unsigned int hi = m[yh*WPR+2];
            if (lo | hi) {
                int dx = nearest_dx(lo, hi, x);
                best = min(best, dy*dy + dx*dx);
            }
        }
    }
    return best;
}

// squared distance from (y,x) to FARTHEST set pixel (empty-set diameter
// fallback only; dead for 50%-dense random masks).
__device__ __forceinline__ int farthest2d(const unsigned int* m, int y, int x) {
    int best = 0;
    for (int yy = 0; yy < HH; ++yy) {
        unsigned long long lo = (unsigned long long)m[yy*WPR] |
                                ((unsigned long long)m[yy*WPR+1] << 32);
        unsigned int hi = m[yy*WPR+2];
        if (lo | hi) {
            int fd = farthest_dx(lo, hi, x);
            int dy = yy - y;
            best = max(best, dy*dy + fd*fd);
        }
    }
    return best;
}

// 192 blocks = 16 images x 12 stripes. Each block redundantly builds its
// image's bitmasks in LDS (L2-served), searches its 768-px stripe, reduces,
// publishes via device-scope atomicMax; the last block finalizes the mean.
__global__ __launch_bounds__(TPB) void hausdorff_fused(const float* __restrict__ pred,
                                                       const float* __restrict__ targ,
                                                       int* __restrict__ gAB,
                                                       int* __restrict__ gBA,
                                                       int* __restrict__ cnt,
                                                       float* __restrict__ out) {
    int blk    = blockIdx.x;
    int img    = blk / STRIPES;
    int stripe = blk - img * STRIPES;
    int tid    = threadIdx.x;

    __shared__ unsigned int sA[WPI], sB[WPI];
    __shared__ int redAB, redBA, fA, fB, isLast;
    if (tid == 0) { redAB = -1; redBA = -1; fA = 0; fB = 0; }
    __syncthreads();

    // ---- build masks: each thread packs 32-px words via 8 float4 loads
    for (int w = tid; w < 2 * WPI; w += TPB) {
        int set = w >= WPI;
        int ww  = set ? w - WPI : w;
        const float* src = (set ? targ : pred) + img * HN + 32 * ww;
        const float4* v4 = reinterpret_cast<const float4*>(src);
        unsigned int bits = 0;
        #pragma unroll
        for (int j = 0; j < 8; ++j) {
            float4 v = v4[j];
            if (v.x >= 0.5f) bits |= 1u << (4*j + 0);
            if (v.y >= 0.5f) bits |= 1u << (4*j + 1);
            if (v.z >= 0.5f) bits |= 1u << (4*j + 2);
            if (v.w >= 0.5f) bits |= 1u << (4*j + 3);
        }
        (set ? sB : sA)[ww] = bits;
        if (bits) { if (set) fB = 1; else fA = 1; }   // benign same-value race
    }
    __syncthreads();

    bool anyA = fA != 0, anyB = fB != 0;              // block-uniform
    int lAB = -1, lBA = -1;
    int y0 = stripe * ROWS_PER;

    if (anyA && anyB) {
        for (int k = 0; k < PX_PER; k += TPB) {
            int li = k + tid;
            int ry = li / HW;
            int y  = y0 + ry;
            int x  = li - ry * HW;
            bool a = (sA[y*WPR + (x>>5)] >> (x & 31)) & 1u;
            bool b = (sB[y*WPR + (x>>5)] >> (x & 31)) & 1u;
            if (a) lAB = max(lAB, search2d(sB, y, x));   // A-point -> set B
            if (b) lBA = max(lBA, search2d(sA, y, x));   // B-point -> set A
        }
    } else if (anyA) {        // B empty -> diameter of A (dead path, kept exact)
        for (int k = 0; k < PX_PER; k += TPB) {
            int li = k + tid;
            int ry = li / HW;
            int y  = y0 + ry;
            int x  = li - ry * HW;
            if ((sA[y*WPR + (x>>5)] >> (x & 31)) & 1u)
                lAB = max(lAB, farthest2d(sA, y, x));
        }
    } else if (anyB) {        // A empty -> diameter of B
        for (int k = 0; k < PX_PER; k += TPB) {
            int li = k + tid;
            int ry = li / HW;
            int y  = y0 + ry;
            int x  = li - ry * HW;
            if ((sB[y*WPR + (x>>5)] >> (x & 31)) & 1u)
                lBA = max(lBA, farthest2d(sB, y, x));
        }
    }

    // ---- wave shuffle max-reduce, then per-wave LDS atomic
    #pragma unroll
    for (int off = 32; off >= 1; off >>= 1) {
        lAB = max(lAB, __shfl_down(lAB, off, 64));
        lBA = max(lBA, __shfl_down(lBA, off, 64));
    }
    if ((tid & 63) == 0) {
        atomicMax(&redAB, lAB);
        atomicMax(&redBA, lBA);
    }
    __syncthreads();

    // ---- publish + last-block detection (device-scope, G16-safe)
    if (tid == 0) {
        atomicMax(&gAB[img], redAB);
        atomicMax(&gBA[img], redBA);
        __threadfence();
        int old = atomicAdd(cnt, 1);         // cnt seeded to -1; last sees NBLK-2
        isLast = (old == NBLK - 2);
    }
    __syncthreads();

    // ---- last block: empty-rule-uniform hd = sqrt(max(AB, BA, 0)); mean
    if (isLast) {
        float hd = 0.0f;
        if (tid < HB) {
            int vAB = atomicMax(&gAB[tid], INT_MIN);   // atomic read
            int vBA = atomicMax(&gBA[tid], INT_MIN);
            hd = sqrtf((float)max(max(vAB, vBA), 0));
        }
        if (tid < 64) {
            #pragma unroll
            for (int off = 8; off >= 1; off >>= 1)
                hd += __shfl_down(hd, off, 16);
            if (tid == 0) out[0] = hd * (1.0f / HB);
        }
    }
}

extern "C" void kernel_launch(void* const* d_in, const int* in_sizes, int n_in,
                              void* d_out, int out_size, void* d_ws, size_t ws_size,
                              hipStream_t stream) {
    const float* pred = (const float*)d_in[0];
    const float* targ = (const float*)d_in[1];
    float* out = (float*)d_out;

    // ws: gAB int[16] | gBA int[16] | cnt int[1]  -> all seeded to -1 (0xFF)
    int* gAB = (int*)d_ws;
    int* gBA = gAB + HB;
    int* cnt = gBA + HB;
    hipMemsetAsync(d_ws, 0xFF, (2 * HB + 1) * sizeof(int), stream);

    hausdorff_fused<<<NBLK, TPB, 0, stream>>>(pred, targ, gAB, gBA, cnt, out);
}